// Round 1
// baseline (648.684 us; speedup 1.0000x reference)
//
#include <hip/hip_runtime.h>

#define FIN 256
#define H1 8
#define C1 16
#define D1 128   // H1*C1
#define D2 40

static __device__ __forceinline__ float lrelu(float x){ return x > 0.f ? x : 0.2f*x; }

// ---------------- CSR build ----------------
__global__ void hist_k(const int* __restrict__ dst, int E, int* __restrict__ deg){
  int i = blockIdx.x*blockDim.x + threadIdx.x;
  if (i < E) atomicAdd(&deg[dst[i]], 1);
}

__global__ __launch_bounds__(1024) void scan_k(int* __restrict__ off, int* __restrict__ cursor, int N){
  __shared__ int sums[1024];
  int t = threadIdx.x;
  int CH = (N + 1023)/1024;
  int lo = t*CH; int hi = lo + CH;
  if (lo > N) lo = N;
  if (hi > N) hi = N;
  int s = 0;
  for (int i = lo; i < hi; ++i) s += off[i];
  sums[t] = s; __syncthreads();
  for (int o = 1; o < 1024; o <<= 1){
    int v = (t >= o) ? sums[t-o] : 0;
    __syncthreads();
    sums[t] += v;
    __syncthreads();
  }
  int run = (t == 0) ? 0 : sums[t-1];
  for (int i = lo; i < hi; ++i){
    int d = off[i];
    off[i] = run; cursor[i] = run; run += d;
  }
  if (t == 1023) off[N] = sums[1023];
}

__global__ void scatter_k(const int* __restrict__ src, const int* __restrict__ dst, int E,
                          int* __restrict__ cursor, int* __restrict__ csr){
  int i = blockIdx.x*blockDim.x + threadIdx.x;
  if (i < E){
    int p = atomicAdd(&cursor[dst[i]], 1);
    csr[p] = src[i];
  }
}

// ---------------- GEMM1: h1 = x @ W1, fused attention dots ----------------
__global__ __launch_bounds__(256) void gemm1_k(const float* __restrict__ x, const float* __restrict__ W,
    const float* __restrict__ attS, const float* __restrict__ attD,
    float* __restrict__ h1, float* __restrict__ aS, float* __restrict__ aD, int N){
  __shared__ float As[16][65];     // [k][m], padded
  __shared__ float Bs[16][128];    // [k][n]
  int tid = threadIdx.x;
  int tx = tid & 15, ty = tid >> 4;
  int m0 = blockIdx.x * 64;
  float acc[4][8];
  #pragma unroll
  for (int i=0;i<4;i++)
    #pragma unroll
    for (int j=0;j<8;j++) acc[i][j]=0.f;

  for (int k0 = 0; k0 < FIN; k0 += 16){
    #pragma unroll
    for (int l=0;l<4;l++){
      int idx = tid + l*256;          // 0..1023 over [64 rows][16 cols]
      int r = idx >> 4, c = idx & 15;
      int gr = m0 + r;
      As[c][r] = (gr < N) ? x[gr*FIN + k0 + c] : 0.f;
    }
    #pragma unroll
    for (int l=0;l<8;l++){
      int idx = tid + l*256;          // 0..2047 over [16 rows][128 cols]
      int r = idx >> 7, c = idx & 127;
      Bs[r][c] = W[(k0+r)*D1 + c];
    }
    __syncthreads();
    #pragma unroll
    for (int k=0;k<16;k++){
      float a[4], b[8];
      #pragma unroll
      for (int i=0;i<4;i++) a[i] = As[k][ty*4+i];
      #pragma unroll
      for (int j=0;j<8;j++) b[j] = Bs[k][tx*8+j];
      #pragma unroll
      for (int i=0;i<4;i++)
        #pragma unroll
        for (int j=0;j<8;j++) acc[i][j] += a[i]*b[j];
    }
    __syncthreads();
  }

  int h = tx >> 1;
  int ccb = (tx & 1) * 8;
  #pragma unroll
  for (int i=0;i<4;i++){
    int r = m0 + ty*4 + i;
    if (r < N){
      float4 v0 = make_float4(acc[i][0],acc[i][1],acc[i][2],acc[i][3]);
      float4 v1 = make_float4(acc[i][4],acc[i][5],acc[i][6],acc[i][7]);
      *(float4*)&h1[r*D1 + tx*8]     = v0;
      *(float4*)&h1[r*D1 + tx*8 + 4] = v1;
      float pS=0.f, pD=0.f;
      #pragma unroll
      for (int j=0;j<8;j++){
        pS += acc[i][j]*attS[h*C1+ccb+j];
        pD += acc[i][j]*attD[h*C1+ccb+j];
      }
      pS += __shfl_xor(pS,1);
      pD += __shfl_xor(pD,1);
      if ((tx & 1) == 0){ aS[r*H1+h] = pS; aD[r*H1+h] = pD; }
    }
  }
}

// ---------------- node1: online-softmax aggregation + bias + elu ----------------
__global__ __launch_bounds__(64) void node1_k(const float* __restrict__ h1,
    const float* __restrict__ aS, const float* __restrict__ aD,
    const int* __restrict__ off, const int* __restrict__ csr,
    const float* __restrict__ b1, float* __restrict__ x2, int N){
  int n = blockIdx.x;
  int lane = threadIdx.x;
  int c0 = lane, c1 = lane + 64;
  int hA = lane >> 4, hB = 4 + (lane >> 4);
  float adA = aD[n*H1+hA], adB = aD[n*H1+hB];
  // self loop first
  float eA = lrelu(aS[n*H1+hA] + adA);
  float eB = lrelu(aS[n*H1+hB] + adB);
  float mA = eA, mB = eB, dA = 1.f, dB = 1.f;
  float acc0 = h1[n*D1+c0], acc1 = h1[n*D1+c1];
  int s0 = off[n], s1 = off[n+1];
  for (int i = s0; i < s1; ++i){
    int s = csr[i];
    float e_A = lrelu(aS[s*H1+hA] + adA);
    float e_B = lrelu(aS[s*H1+hB] + adB);
    float h0 = h1[s*D1+c0], hv1 = h1[s*D1+c1];
    float nmA = fmaxf(mA, e_A);
    float scA = __expf(mA - nmA);
    float pA  = __expf(e_A - nmA);
    dA = dA*scA + pA; mA = nmA; acc0 = acc0*scA + pA*h0;
    float nmB = fmaxf(mB, e_B);
    float scB = __expf(mB - nmB);
    float pB  = __expf(e_B - nmB);
    dB = dB*scB + pB; mB = nmB; acc1 = acc1*scB + pB*hv1;
  }
  float o0 = acc0/dA + b1[c0];
  float o1 = acc1/dB + b1[c1];
  x2[n*D1+c0] = o0 > 0.f ? o0 : __expf(o0) - 1.f;
  x2[n*D1+c1] = o1 > 0.f ? o1 : __expf(o1) - 1.f;
}

// ---------------- GEMM2: h2 = x2 @ W2, fused attention dots ----------------
__global__ __launch_bounds__(256) void gemm2_k(const float* __restrict__ x2, const float* __restrict__ W2,
    const float* __restrict__ attS2, const float* __restrict__ attD2,
    float* __restrict__ h2, float* __restrict__ aS2, float* __restrict__ aD2, int N){
  __shared__ float Ws[128*D2];     // 20 KB
  __shared__ float Xs[32][129];    // 16.5 KB, padded
  int tid = threadIdx.x;
  for (int i = tid; i < 128*D2; i += 256) Ws[i] = W2[i];
  int r0 = blockIdx.x*32;
  for (int i = tid; i < 32*128; i += 256){
    int r = i >> 7, c = i & 127;
    Xs[r][c] = (r0 + r < N) ? x2[(r0+r)*D1 + c] : 0.f;
  }
  __syncthreads();
  int r = tid >> 3, g = tid & 7;   // r: 0..31 row, g: 0..7 col-group (5 cols each)
  float acc[5] = {0.f,0.f,0.f,0.f,0.f};
  for (int k = 0; k < 128; ++k){
    float xv = Xs[r][k];
    #pragma unroll
    for (int j=0;j<5;j++) acc[j] += xv * Ws[k*D2 + g*5 + j];
  }
  int row = r0 + r;
  float pS = 0.f, pD = 0.f;
  #pragma unroll
  for (int j=0;j<5;j++){ pS += acc[j]*attS2[g*5+j]; pD += acc[j]*attD2[g*5+j]; }
  #pragma unroll
  for (int o=4;o>0;o>>=1){ pS += __shfl_down(pS,o,8); pD += __shfl_down(pD,o,8); }
  if (row < N){
    #pragma unroll
    for (int j=0;j<5;j++) h2[row*D2 + g*5 + j] = acc[j];
    if (g == 0){ aS2[row] = pS; aD2[row] = pD; }
  }
}

// ---------------- node2: online-softmax aggregation + bias → out ----------------
__global__ __launch_bounds__(64) void node2_k(const float* __restrict__ h2,
    const float* __restrict__ aS2, const float* __restrict__ aD2,
    const int* __restrict__ off, const int* __restrict__ csr,
    const float* __restrict__ b2, float* __restrict__ out, int N){
  int n = blockIdx.x;
  int lane = threadIdx.x;
  float ad = aD2[n];
  float e = lrelu(aS2[n] + ad);
  float m = e, d = 1.f;
  float acc = (lane < D2) ? h2[n*D2+lane] : 0.f;
  int s0 = off[n], s1 = off[n+1];
  for (int i = s0; i < s1; ++i){
    int s = csr[i];
    float ee = lrelu(aS2[s] + ad);
    float nm = fmaxf(m, ee);
    float sc = __expf(m - nm);
    float p  = __expf(ee - nm);
    float hv = (lane < D2) ? h2[s*D2+lane] : 0.f;
    d = d*sc + p; m = nm; acc = acc*sc + p*hv;
  }
  if (lane < D2) out[n*D2+lane] = acc/d + b2[lane];
}

extern "C" void kernel_launch(void* const* d_in, const int* in_sizes, int n_in,
                              void* d_out, int out_size, void* d_ws, size_t ws_size,
                              hipStream_t stream){
  const float* x     = (const float*)d_in[0];
  const int*   ei    = (const int*)d_in[1];
  const float* W1    = (const float*)d_in[2];
  const float* attS1 = (const float*)d_in[3];
  const float* attD1 = (const float*)d_in[4];
  const float* b1    = (const float*)d_in[5];
  const float* W2    = (const float*)d_in[6];
  const float* attS2 = (const float*)d_in[7];
  const float* attD2 = (const float*)d_in[8];
  const float* b2    = (const float*)d_in[9];
  float* out = (float*)d_out;

  int N = in_sizes[0] / FIN;   // 50000
  int E = in_sizes[1] / 2;     // 1600000
  const int* src = ei;
  const int* dst = ei + E;

  char* ws = (char*)d_ws;
  size_t o = 0;
  auto alloc = [&](size_t bytes) -> void* {
    void* p = ws + o;
    o += (bytes + 255) & ~size_t(255);
    return p;
  };
  float* h1  = (float*)alloc((size_t)N*D1*sizeof(float));
  float* x2  = (float*)alloc((size_t)N*D1*sizeof(float));
  float* h2  = (float*)alloc((size_t)N*D2*sizeof(float));
  float* aS1 = (float*)alloc((size_t)N*H1*sizeof(float));
  float* aD1 = (float*)alloc((size_t)N*H1*sizeof(float));
  float* aS2 = (float*)alloc((size_t)N*sizeof(float));
  float* aD2 = (float*)alloc((size_t)N*sizeof(float));
  int*   off = (int*)alloc((size_t)(N+1)*sizeof(int));
  int*   cur = (int*)alloc((size_t)N*sizeof(int));
  int*   csr = (int*)alloc((size_t)E*sizeof(int));

  hipMemsetAsync(off, 0, (size_t)(N+1)*sizeof(int), stream);
  hist_k<<<(E+255)/256, 256, 0, stream>>>(dst, E, off);
  scan_k<<<1, 1024, 0, stream>>>(off, cur, N);
  scatter_k<<<(E+255)/256, 256, 0, stream>>>(src, dst, E, cur, csr);
  gemm1_k<<<(N+63)/64, 256, 0, stream>>>(x, W1, attS1, attD1, h1, aS1, aD1, N);
  node1_k<<<N, 64, 0, stream>>>(h1, aS1, aD1, off, csr, b1, x2, N);
  gemm2_k<<<(N+31)/32, 256, 0, stream>>>(x2, W2, attS2, attD2, h2, aS2, aD2, N);
  node2_k<<<N, 64, 0, stream>>>(h2, aS2, aD2, off, csr, b2, out, N);
}